// Round 2
// baseline (625.198 us; speedup 1.0000x reference)
//
#include <hip/hip_runtime.h>
#include <hip/hip_bf16.h>

// ParallelMLPs: N=32 experts, T=4096, D=256, H=512, fp32 in/out.
// out[e,t,:] = silu(x[e,t,:]·W1[e]^T + b1[e])·W2[e]^T + b2[e] + x[e,t,:]
//
// Strategy: fused per-(expert,64-token-tile) block; bf16x3 split (hi/lo) MFMA
// for fp32-grade accuracy (~1e-4 absmax) since CDNA4 has no fp32 MFMA.
// X A-fragments live in REGISTERS (loaded once, reused by all 16 H-chunks);
// weights staged per-chunk global->regs (issued early, T14) ->split->LDS.

#define N_EXP 32
#define T_TOK 4096
#define D_MOD 256
#define H_HID 512

#define BT 64                 // token rows per block
#define HC 32                 // hidden-chunk (one K=32 MFMA step for GEMM2)
#define NCHUNK (H_HID / HC)   // 16
#define NTHREADS 256          // 4 waves

// LDS pitches (bf16 elems). Row strides map to 2-way-max bank aliasing (free, m136).
#define WPITCH  264   // W1 chunk rows: 528 B  (132 banks ≡ 4 mod 32)
#define W2PITCH 40    // W2 rows: 80 B         (20 banks ≡ 20 mod 32)
#define APITCH  40    // act rows: 80 B

typedef __attribute__((ext_vector_type(8))) __bf16 bf16x8;
typedef __attribute__((ext_vector_type(4))) float  f32x4;

__device__ __forceinline__ f32x4 mfma16(bf16x8 a, bf16x8 b, f32x4 c) {
  return __builtin_amdgcn_mfma_f32_16x16x32_bf16(a, b, c, 0, 0, 0);
}

// fp32[8] -> bf16 hi + bf16 lo (residual), RNE both.
__device__ __forceinline__ void split8(const float v[8], bf16x8& hi, bf16x8& lo) {
#pragma unroll
  for (int j = 0; j < 8; ++j) {
    float f = v[j];
    __bf16 h = (__bf16)f;
    hi[j] = h;
    lo[j] = (__bf16)(f - (float)h);
  }
}

__global__ __launch_bounds__(NTHREADS, 1)
void pmlp_fused(const float* __restrict__ x, const float* __restrict__ W1,
                const float* __restrict__ b1, const float* __restrict__ W2,
                const float* __restrict__ b2, float* __restrict__ out) {
  // 86 KB LDS -> 1 block/CU (structural; X no longer staged in LDS)
  __shared__ __bf16 W1h[HC * WPITCH],     W1l[HC * WPITCH];      // 33792 B
  __shared__ __bf16 W2h[D_MOD * W2PITCH], W2l[D_MOD * W2PITCH];  // 40960 B
  __shared__ __bf16 Ah[BT * APITCH],      Al[BT * APITCH];       // 10240 B
  __shared__ float  b1s[H_HID], b2s[D_MOD];                      // 3072 B

  const int tid = threadIdx.x;

  // XCD-aware mapping: expert e's 64 blocks land on one XCD -> its 1 MB of
  // weights stays L2-resident there (64x weight reuse served from L2).
  const int p    = blockIdx.x;                // 0..2047
  const int xcd  = p & 7;
  const int slot = p >> 3;                    // 0..255
  const int e    = xcd + ((slot >> 6) << 3);  // expert 0..31
  const int ti   = slot & 63;                 // 64-token tile within expert

  const float* xb  = x  + ((size_t)e * T_TOK + (size_t)ti * BT) * D_MOD;
  const float* w1b = W1 + (size_t)e * H_HID * D_MOD;
  const float* w2b = W2 + (size_t)e * D_MOD * H_HID;
  float*       ob  = out + ((size_t)e * T_TOK + (size_t)ti * BT) * D_MOD;

  // biases -> LDS (written before first barrier, never overwritten)
  b2s[tid]       = b2[e * D_MOD + tid];
  b1s[tid]       = b1[e * H_HID + tid];
  b1s[tid + 256] = b1[e * H_HID + tid + 256];

  const int l    = tid & 63;
  const int w    = tid >> 6;        // wave 0..3
  const int lrow = l & 15;          // MFMA frag row/col lane index
  const int lk8  = (l >> 4) << 3;   // k-offset within a 32-wide k-step
  const int lr4  = (l >> 4) << 2;   // C/D row group base

  // GEMM1 wave tiling of the 64x32 h-chunk: waves {0,1}x{0,1} -> (row32)x(col16)
  const int g1_r = (w & 1) << 5;    // 0 / 32
  const int g1_c = (w >> 1) << 4;   // 0 / 16

  // ---- X A-fragments -> registers, hi/lo (reused by all 16 chunks) ----
  // Frag layout (guide §3 verified): lane l holds A[m=l&15][k=lk8..lk8+7].
  bf16x8 xh[2][8], xl[2][8];        // [row-frag mf][k-step kk] : 128 VGPR
#pragma unroll
  for (int mf = 0; mf < 2; ++mf)
#pragma unroll
    for (int kk = 0; kk < 8; ++kk) {
      const float* s = xb + (g1_r + (mf << 4) + lrow) * D_MOD + (kk << 5) + lk8;
      float4 u0 = *(const float4*)s;
      float4 u1 = *(const float4*)(s + 4);
      float v[8] = {u0.x, u0.y, u0.z, u0.w, u1.x, u1.y, u1.z, u1.w};
      split8(v, xh[mf][kk], xl[mf][kk]);
    }

  // ---- weight staging: global->regs (issued early) then split->LDS ----
  float s1[4][8], s2[4][8];         // 64 VGPR in-flight staging
  auto loadW = [&](int c) {
#pragma unroll
    for (int k2 = 0; k2 < 4; ++k2) {
      int g = tid + (k2 << 8);
      {
        int row = g >> 5, col = (g & 31) << 3;                  // W1c: [32][256]
        const float* sp = w1b + (size_t)(c * HC + row) * D_MOD + col;
        float4 u0 = *(const float4*)sp, u1 = *(const float4*)(sp + 4);
        s1[k2][0]=u0.x; s1[k2][1]=u0.y; s1[k2][2]=u0.z; s1[k2][3]=u0.w;
        s1[k2][4]=u1.x; s1[k2][5]=u1.y; s1[k2][6]=u1.z; s1[k2][7]=u1.w;
      }
      {
        int row = g >> 2, col = (g & 3) << 3;                   // W2c: [256][32]
        const float* sp = w2b + (size_t)row * H_HID + c * HC + col;
        float4 u0 = *(const float4*)sp, u1 = *(const float4*)(sp + 4);
        s2[k2][0]=u0.x; s2[k2][1]=u0.y; s2[k2][2]=u0.z; s2[k2][3]=u0.w;
        s2[k2][4]=u1.x; s2[k2][5]=u1.y; s2[k2][6]=u1.z; s2[k2][7]=u1.w;
      }
    }
  };
  auto writeW = [&]() {
#pragma unroll
    for (int k2 = 0; k2 < 4; ++k2) {
      int g = tid + (k2 << 8);
      {
        int row = g >> 5, col = (g & 31) << 3;
        bf16x8 hi, lo; split8(s1[k2], hi, lo);
        *(bf16x8*)&W1h[row * WPITCH + col] = hi;
        *(bf16x8*)&W1l[row * WPITCH + col] = lo;
      }
      {
        int row = g >> 2, col = (g & 3) << 3;
        bf16x8 hi, lo; split8(s2[k2], hi, lo);
        *(bf16x8*)&W2h[row * W2PITCH + col] = hi;
        *(bf16x8*)&W2l[row * W2PITCH + col] = lo;
      }
    }
  };

  const f32x4 fz = {0.f, 0.f, 0.f, 0.f};
  f32x4 acc2[4][4];                 // per-wave 64x64 fp32 output tile (64 VGPR)
#pragma unroll
  for (int mf = 0; mf < 4; ++mf)
#pragma unroll
    for (int nf = 0; nf < 4; ++nf) acc2[mf][nf] = fz;

  loadW(0);
  writeW();
  __syncthreads();

  for (int c = 0; c < NCHUNK; ++c) {
    if (c < NCHUNK - 1) loadW(c + 1);   // issue next chunk's global loads NOW (T14)

    // ---- GEMM1: h-chunk[64x32] = X(regs) . W1c^T, bf16x3 ----
    f32x4 acc1[2] = {fz, fz};
#pragma unroll
    for (int kk = 0; kk < 8; ++kk) {
      int k = (kk << 5) + lk8;
      bf16x8 bh = *(const bf16x8*)&W1h[(g1_c + lrow) * WPITCH + k];
      bf16x8 bl = *(const bf16x8*)&W1l[(g1_c + lrow) * WPITCH + k];
#pragma unroll
      for (int mf = 0; mf < 2; ++mf) {
        acc1[mf] = mfma16(xh[mf][kk], bh, acc1[mf]);
        acc1[mf] = mfma16(xh[mf][kk], bl, acc1[mf]);
        acc1[mf] = mfma16(xl[mf][kk], bh, acc1[mf]);
      }
    }
    // bias + silu -> split -> act LDS (C/D layout: col=l&15, row=lr4+r)
    float b1v = b1s[c * HC + g1_c + lrow];
#pragma unroll
    for (int mf = 0; mf < 2; ++mf)
#pragma unroll
      for (int r = 0; r < 4; ++r) {
        float hv = acc1[mf][r] + b1v;
        hv = hv / (1.f + __expf(-hv));        // silu
        __bf16 hh = (__bf16)hv;
        int arow = g1_r + (mf << 4) + lr4 + r;
        Ah[arow * APITCH + g1_c + lrow] = hh;
        Al[arow * APITCH + g1_c + lrow] = (__bf16)(hv - (float)hh);
      }
    __syncthreads();                  // A visible to all waves

    // ---- GEMM2: acc2 += act(64x32) . W2c^T(32->256), one k-step ----
    bf16x8 bh2[4], bl2[4];
#pragma unroll
    for (int nf = 0; nf < 4; ++nf) {
      int dcol = (w << 6) + (nf << 4) + lrow;
      bh2[nf] = *(const bf16x8*)&W2h[dcol * W2PITCH + lk8];
      bl2[nf] = *(const bf16x8*)&W2l[dcol * W2PITCH + lk8];
    }
#pragma unroll
    for (int mf = 0; mf < 4; ++mf) {
      bf16x8 ah = *(const bf16x8*)&Ah[((mf << 4) + lrow) * APITCH + lk8];
      bf16x8 al = *(const bf16x8*)&Al[((mf << 4) + lrow) * APITCH + lk8];
#pragma unroll
      for (int nf = 0; nf < 4; ++nf) {
        acc2[mf][nf] = mfma16(ah, bh2[nf], acc2[mf][nf]);
        acc2[mf][nf] = mfma16(ah, bl2[nf], acc2[mf][nf]);
        acc2[mf][nf] = mfma16(al, bh2[nf], acc2[mf][nf]);
      }
    }
    __syncthreads();                  // W1/W2/A free to overwrite

    if (c < NCHUNK - 1) {
      writeW();                       // split + LDS-write chunk c+1 (vmcnt waits here)
      __syncthreads();                // W visible before next GEMM1
    }
  }

  // ---- epilogue: out = acc2 + b2 + x (residual) ----
#pragma unroll
  for (int mf = 0; mf < 4; ++mf)
#pragma unroll
    for (int r = 0; r < 4; ++r) {
      int trow = (mf << 4) + lr4 + r;
#pragma unroll
      for (int nf = 0; nf < 4; ++nf) {
        int dcol = (w << 6) + (nf << 4) + lrow;
        ob[trow * D_MOD + dcol] = acc2[mf][nf][r] + b2s[dcol] + xb[trow * D_MOD + dcol];
      }
    }
}

extern "C" void kernel_launch(void* const* d_in, const int* in_sizes, int n_in,
                              void* d_out, int out_size, void* d_ws, size_t ws_size,
                              hipStream_t stream) {
  const float* x  = (const float*)d_in[0];
  const float* W1 = (const float*)d_in[1];
  const float* b1 = (const float*)d_in[2];
  const float* W2 = (const float*)d_in[3];
  const float* b2 = (const float*)d_in[4];
  float* out = (float*)d_out;

  dim3 grid(N_EXP * (T_TOK / BT));   // 2048 blocks
  dim3 block(NTHREADS);
  hipLaunchKernelGGL(pmlp_fused, grid, block, 0, stream, x, W1, b1, W2, b2, out);
}

// Round 4
// 493.996 us; speedup vs baseline: 1.2656x; 1.2656x over previous
//
#include <hip/hip_runtime.h>
#include <hip/hip_bf16.h>

// ParallelMLPs: N=32 experts, T=4096, D=256, H=512, fp32 in/out.
// out[e,t,:] = silu(x[e,t,:].W1[e]^T + b1).W2[e]^T + b2 + x
//
// bf16x3 (hi/lo split) MFMA path. Weights pre-split+pre-swizzled into chunk-
// contiguous bf16 images in d_ws; the fused kernel stages them with
// global_load_lds (no VGPR round-trip) under raw-barrier counted-vmcnt
// pipelining (T4). X A-fragments live in registers across all 16 chunks.

#define N_EXP 32
#define T_TOK 4096
#define D_MOD 256
#define H_HID 512

#define BT 64
#define HC 32
#define NCHUNK 16
#define NTHREADS 256

#define NWELEM 4194304ull                 // elems per weight image (32*512*256)
#define WS_NEEDED (8ull * NWELEM)         // 4 images * NWELEM * 2B = 33,554,432 B

typedef __attribute__((ext_vector_type(8))) __bf16 bf16x8;
typedef __attribute__((ext_vector_type(4))) __bf16 bf16x4;
typedef __attribute__((ext_vector_type(4))) float  f32x4;
union U4 { uint4 q; bf16x8 v; };

static __device__ __forceinline__ f32x4 mfma16(bf16x8 a, bf16x8 b, f32x4 c) {
  return __builtin_amdgcn_mfma_f32_16x16x32_bf16(a, b, c, 0, 0, 0);
}

static __device__ __forceinline__ void split8(const float v[8], bf16x8& hi, bf16x8& lo) {
#pragma unroll
  for (int j = 0; j < 8; ++j) {
    float f = v[j];
    __bf16 h = (__bf16)f;
    hi[j] = h;
    lo[j] = (__bf16)(f - (float)h);
  }
}

// async global->LDS, 16B/lane; LDS dest must be wave-uniform (HW adds lane*16)
static __device__ __forceinline__ void gl_lds16(const __bf16* g, __bf16* l) {
  __builtin_amdgcn_global_load_lds(
      (const __attribute__((address_space(1))) void*)g,
      (__attribute__((address_space(3))) void*)l, 16, 0, 0);
}

#define BAR_LGKM() do { asm volatile("s_waitcnt lgkmcnt(0)" ::: "memory"); \
  __builtin_amdgcn_s_barrier(); __builtin_amdgcn_sched_barrier(0); } while (0)
#define BAR_VM(n) do { asm volatile("s_waitcnt vmcnt(" #n ")" ::: "memory"); \
  __builtin_amdgcn_s_barrier(); __builtin_amdgcn_sched_barrier(0); } while (0)

// ---------------------------------------------------------------------------
// Pre-pass: split W1,W2 fp32 -> bf16 hi/lo, laid out chunk-contiguous and
// XOR-swizzled exactly as the fused kernel's LDS wants them, so staging is a
// linear global_load_lds copy (m173: swizzle on the global side, LDS linear).
// ws elems: [W1h | W1l | W2h | W2l], each NWELEM.
//  W1 image: unit(e,hrow,u) -> (e*512+hrow)*32 + (u ^ (hrow&7))        u=col>>3
//  W2 image: unit(e,d,u)    -> ((e*16+c)*256+d)*4 + ((u&3) ^ ((d>>1)&3)), c=u>>2
// ---------------------------------------------------------------------------
__global__ __launch_bounds__(256)
void presplit_w(const float* __restrict__ W1, const float* __restrict__ W2,
                __bf16* __restrict__ ws) {
  unsigned U = blockIdx.x * 256 + threadIdx.x;   // 0..524287 (one 8-elem unit)
  {
    unsigned row = U >> 5;                       // e*512 + hrow
    unsigned u   = U & 31;
    const float* src = W1 + ((size_t)U << 3);
    float4 a0 = *(const float4*)src, a1 = *(const float4*)(src + 4);
    float v[8] = {a0.x, a0.y, a0.z, a0.w, a1.x, a1.y, a1.z, a1.w};
    bf16x8 hi, lo; split8(v, hi, lo);
    size_t dst = (((size_t)row << 5) | (u ^ (row & 7))) << 3;
    *(bf16x8*)(ws + dst)          = hi;
    *(bf16x8*)(ws + NWELEM + dst) = lo;
  }
  {
    unsigned r = U >> 6;                         // e*256 + d
    unsigned e = r >> 8, d = r & 255;
    unsigned u = U & 63;
    unsigned c = u >> 2, uc = u & 3;
    const float* src = W2 + ((size_t)U << 3);
    float4 a0 = *(const float4*)src, a1 = *(const float4*)(src + 4);
    float v[8] = {a0.x, a0.y, a0.z, a0.w, a1.x, a1.y, a1.z, a1.w};
    bf16x8 hi, lo; split8(v, hi, lo);
    size_t dst = (((((size_t)((e << 4) + c) << 8) + d) << 2) | (uc ^ ((d >> 1) & 3))) << 3;
    *(bf16x8*)(ws + 2 * NWELEM + dst) = hi;
    *(bf16x8*)(ws + 3 * NWELEM + dst) = lo;
  }
}

// ---------------------------------------------------------------------------
// Main fused kernel (presplit path)
// ---------------------------------------------------------------------------
__global__ __launch_bounds__(NTHREADS, 2)
void pmlp_fused(const float* __restrict__ x, const float* __restrict__ b1g,
                const float* __restrict__ b2g, float* __restrict__ out,
                const __bf16* __restrict__ wsp) {
  // 74 KB LDS -> 2 blocks/CU
  __shared__ __bf16 W1h[HC * D_MOD],   W1l[HC * D_MOD];     // 2 x 16 KB (swizzled)
  __shared__ __bf16 W2h[D_MOD * HC],   W2l[D_MOD * HC];     // 2 x 16 KB (swizzled)
  __shared__ unsigned APK[BT * 32];                         // 8 KB packed act hi|lo
  __shared__ float b1s[H_HID];                              // 2 KB

  const int tid = threadIdx.x;

  // XCD swizzle: expert e's 64 blocks land on one XCD -> weights L2-resident
  const int p    = blockIdx.x;
  const int xcd  = p & 7;
  const int slot = p >> 3;
  const int e    = xcd + ((slot >> 6) << 3);
  const int ti   = slot & 63;

  const float* xb = x + ((size_t)e * T_TOK + (size_t)ti * BT) * D_MOD;
  float*       ob = out + ((size_t)e * T_TOK + (size_t)ti * BT) * D_MOD;

  const int l    = tid & 63;
  const int w    = tid >> 6;
  const int lrow = l & 15;
  const int lk8  = (l >> 4) << 3;
  const int lr4  = (l >> 4) << 2;
  const int g1_r = (w & 1) << 5;
  const int g1_c = (w >> 1) << 4;

  // biases -> LDS (only b1 needed in-loop; keeps loop free of stray vmem)
  b1s[tid]       = b1g[e * H_HID + tid];
  b1s[tid + 256] = b1g[e * H_HID + tid + 256];

  // ---- X -> registers (hi/lo), reused by all chunks ----
  bf16x8 xh[2][8], xl[2][8];
#pragma unroll
  for (int mf = 0; mf < 2; ++mf)
#pragma unroll
    for (int kk = 0; kk < 8; ++kk) {
      const float* s = xb + (g1_r + (mf << 4) + lrow) * D_MOD + (kk << 5) + lk8;
      float4 u0 = *(const float4*)s;
      float4 u1 = *(const float4*)(s + 4);
      float v[8] = {u0.x, u0.y, u0.z, u0.w, u1.x, u1.y, u1.z, u1.w};
      split8(v, xh[mf][kk], xl[mf][kk]);
    }

  const __bf16* w1h_img = wsp;
  const __bf16* w1l_img = wsp + NWELEM;
  const __bf16* w2h_img = wsp + 2 * NWELEM;
  const __bf16* w2l_img = wsp + 3 * NWELEM;

  // stage one chunk's W1 (hi+lo, 32 KB) / W2 via global_load_lds: per wave
  // 4 segments x 1KB per buffer; LDS base uniform, global addr per-lane.
  auto stageW1 = [&](int c) {
    size_t gb = ((size_t)(e * NCHUNK + c)) << 13;   // *8192 elems
#pragma unroll
    for (int s = 0; s < 4; ++s) {
      int off = ((w << 2) + s) << 9;                // segment*512 elems
      int go  = off + (l << 3);
      gl_lds16(w1h_img + gb + go, &W1h[off]);
      gl_lds16(w1l_img + gb + go, &W1l[off]);
    }
  };
  auto stageW2 = [&](int c) {
    size_t gb = ((size_t)(e * NCHUNK + c)) << 13;
#pragma unroll
    for (int s = 0; s < 4; ++s) {
      int off = ((w << 2) + s) << 9;
      int go  = off + (l << 3);
      gl_lds16(w2h_img + gb + go, &W2h[off]);
      gl_lds16(w2l_img + gb + go, &W2l[off]);
    }
  };

  const f32x4 fz = {0.f, 0.f, 0.f, 0.f};
  f32x4 acc2[4][4];
#pragma unroll
  for (int mf = 0; mf < 4; ++mf)
#pragma unroll
    for (int nf = 0; nf < 4; ++nf) acc2[mf][nf] = fz;

  // prologue: fence X/bias loads from the counted region, then stage chunk 0
  asm volatile("" ::: "memory");
  stageW1(0);
  stageW2(0);
  asm volatile("s_waitcnt vmcnt(8)\n\ts_waitcnt lgkmcnt(0)" ::: "memory");
  __builtin_amdgcn_s_barrier();
  __builtin_amdgcn_sched_barrier(0);

  for (int c = 0; c < NCHUNK; ++c) {
    // ---- GEMM1: h[64x32] = X(regs) . W1c^T (swizzled LDS), bf16x3 ----
    f32x4 acc1[2] = {fz, fz};
    const int r1 = g1_c + lrow;
#pragma unroll
    for (int kk = 0; kk < 8; ++kk) {
      int uu = (((kk << 2) + (lk8 >> 3)) ^ (r1 & 7)) << 3;
      bf16x8 bh = *(const bf16x8*)&W1h[(r1 << 8) + uu];
      bf16x8 bl = *(const bf16x8*)&W1l[(r1 << 8) + uu];
#pragma unroll
      for (int mf = 0; mf < 2; ++mf) {
        acc1[mf] = mfma16(xh[mf][kk], bh, acc1[mf]);
        acc1[mf] = mfma16(xh[mf][kk], bl, acc1[mf]);
        acc1[mf] = mfma16(xl[mf][kk], bh, acc1[mf]);
      }
    }
    // bias + silu -> pack hi|lo -> APK (unit-XOR swizzle, conflict-free writes)
    float b1v = b1s[c * HC + g1_c + lrow];
    int acol = g1_c + lrow;
#pragma unroll
    for (int mf = 0; mf < 2; ++mf)
#pragma unroll
      for (int r = 0; r < 4; ++r) {
        float hv = acc1[mf][r] + b1v;
        hv = hv / (1.f + __expf(-hv));
        __bf16 hh = (__bf16)hv;
        __bf16 hl = (__bf16)(hv - (float)hh);
        unsigned pk = (unsigned)__builtin_bit_cast(unsigned short, hh) |
                      ((unsigned)__builtin_bit_cast(unsigned short, hl) << 16);
        int arow = g1_r + (mf << 4) + lr4 + r;
        APK[arow * 32 + ((((acol >> 2) ^ (arow & 7)) << 2) | (acol & 3))] = pk;
      }
    BAR_LGKM();                        // B1: APK visible; W1[c] reads done

    if (c < NCHUNK - 1) {
      stageW1(c + 1);                  // W1 LDS free since B1; hides under GEMM2
      BAR_VM(8);                       // B2: W2[c] arrived (oldest 8 retired)
    } else {
      BAR_VM(0);                       // last chunk: drain W2[c]
    }

    // ---- GEMM2: acc2 += act(64x32) . W2c^T ----
    bf16x8 bh2[4], bl2[4];
#pragma unroll
    for (int nf = 0; nf < 4; ++nf) {
      int dcol = (w << 6) + (nf << 4) + lrow;
      int up = (((lk8 >> 3) ^ ((dcol >> 1) & 3)) << 3);
      bh2[nf] = *(const bf16x8*)&W2h[(dcol << 5) + up];
      bl2[nf] = *(const bf16x8*)&W2l[(dcol << 5) + up];
    }
#pragma unroll
    for (int mf = 0; mf < 4; ++mf) {
      int m  = (mf << 4) + lrow;
      int u1 = lk8 >> 2;
      uint4 qa = *(const uint4*)&APK[m * 32 + ((u1 ^ (m & 7)) << 2)];
      uint4 qb = *(const uint4*)&APK[m * 32 + (((u1 + 1) ^ (m & 7)) << 2)];
      U4 ah, al;
      ah.q.x = (qa.x & 0xFFFFu) | (qa.y << 16);
      ah.q.y = (qa.z & 0xFFFFu) | (qa.w << 16);
      ah.q.z = (qb.x & 0xFFFFu) | (qb.y << 16);
      ah.q.w = (qb.z & 0xFFFFu) | (qb.w << 16);
      al.q.x = (qa.x >> 16) | (qa.y & 0xFFFF0000u);
      al.q.y = (qa.z >> 16) | (qa.w & 0xFFFF0000u);
      al.q.z = (qb.x >> 16) | (qb.y & 0xFFFF0000u);
      al.q.w = (qb.z >> 16) | (qb.w & 0xFFFF0000u);
#pragma unroll
      for (int nf = 0; nf < 4; ++nf) {
        acc2[mf][nf] = mfma16(ah.v, bh2[nf], acc2[mf][nf]);
        acc2[mf][nf] = mfma16(ah.v, bl2[nf], acc2[mf][nf]);
        acc2[mf][nf] = mfma16(al.v, bh2[nf], acc2[mf][nf]);
      }
    }
    BAR_LGKM();                        // B3: W2[c]+APK reads done (all waves)

    if (c < NCHUNK - 1) {
      stageW2(c + 1);                  // hides under next GEMM1
      BAR_VM(8);                       // B4: W1[c+1] arrived
    }
  }

  // ---- epilogue: out = acc2 + b2 + x ----
#pragma unroll
  for (int mf = 0; mf < 4; ++mf)
#pragma unroll
    for (int r = 0; r < 4; ++r) {
      int trow = (mf << 4) + lr4 + r;
#pragma unroll
      for (int nf = 0; nf < 4; ++nf) {
        int dcol = (w << 6) + (nf << 4) + lrow;
        ob[trow * D_MOD + dcol] = acc2[mf][nf][r] + b2g[e * D_MOD + dcol]
                                + xb[trow * D_MOD + dcol];
      }
    }
}

// ---------------------------------------------------------------------------
// Fallback (ws too small): round-2 structure — in-kernel split, reg staging,
// __syncthreads. HW-pass-validated layout family.
// ---------------------------------------------------------------------------
#define WPITCH 264
__global__ __launch_bounds__(NTHREADS, 2)
void pmlp_fb(const float* __restrict__ x, const float* __restrict__ W1,
             const float* __restrict__ b1, const float* __restrict__ W2,
             const float* __restrict__ b2, float* __restrict__ out) {
  __shared__ __bf16 W1h[HC * WPITCH], W1l[HC * WPITCH];
  __shared__ __bf16 W2h[D_MOD * 32],  W2l[D_MOD * 32];
  __shared__ unsigned APK[BT * 32];

  const int tid = threadIdx.x;
  const int p = blockIdx.x, xcd = p & 7, slot = p >> 3;
  const int e = xcd + ((slot >> 6) << 3), ti = slot & 63;
  const float* xb = x + ((size_t)e * T_TOK + (size_t)ti * BT) * D_MOD;
  float*       ob = out + ((size_t)e * T_TOK + (size_t)ti * BT) * D_MOD;
  const int l = tid & 63, w = tid >> 6;
  const int lrow = l & 15, lk8 = (l >> 4) << 3, lr4 = (l >> 4) << 2;
  const int g1_r = (w & 1) << 5, g1_c = (w >> 1) << 4;

  bf16x8 xh[2][8], xl[2][8];
#pragma unroll
  for (int mf = 0; mf < 2; ++mf)
#pragma unroll
    for (int kk = 0; kk < 8; ++kk) {
      const float* s = xb + (g1_r + (mf << 4) + lrow) * D_MOD + (kk << 5) + lk8;
      float4 u0 = *(const float4*)s, u1 = *(const float4*)(s + 4);
      float v[8] = {u0.x, u0.y, u0.z, u0.w, u1.x, u1.y, u1.z, u1.w};
      split8(v, xh[mf][kk], xl[mf][kk]);
    }

  float s1[4][8], s2[4][8];
  auto loadW = [&](int c) {
#pragma unroll
    for (int k2 = 0; k2 < 4; ++k2) {
      int g = tid + (k2 << 8);
      int r1 = g >> 5, c1 = (g & 31) << 3;
      int r2 = g >> 2, c2 = (g & 3) << 3;
      const float* sp1 = W1 + ((size_t)e * H_HID + c * HC + r1) * D_MOD + c1;
      const float* sp2 = W2 + ((size_t)e * D_MOD + r2) * H_HID + c * HC + c2;
      float4 u0 = *(const float4*)sp1, u1 = *(const float4*)(sp1 + 4);
      s1[k2][0]=u0.x; s1[k2][1]=u0.y; s1[k2][2]=u0.z; s1[k2][3]=u0.w;
      s1[k2][4]=u1.x; s1[k2][5]=u1.y; s1[k2][6]=u1.z; s1[k2][7]=u1.w;
      float4 v0 = *(const float4*)sp2, v1 = *(const float4*)(sp2 + 4);
      s2[k2][0]=v0.x; s2[k2][1]=v0.y; s2[k2][2]=v0.z; s2[k2][3]=v0.w;
      s2[k2][4]=v1.x; s2[k2][5]=v1.y; s2[k2][6]=v1.z; s2[k2][7]=v1.w;
    }
  };
  auto writeW = [&]() {
#pragma unroll
    for (int k2 = 0; k2 < 4; ++k2) {
      int g = tid + (k2 << 8);
      int r1 = g >> 5, c1 = (g & 31) << 3;
      int r2 = g >> 2, u2 = g & 3;
      int sw2 = ((u2 ^ (r2 & 3)) << 3);
      bf16x8 hi, lo;
      split8(s1[k2], hi, lo);
      *(bf16x8*)&W1h[r1 * WPITCH + c1] = hi;
      *(bf16x8*)&W1l[r1 * WPITCH + c1] = lo;
      split8(s2[k2], hi, lo);
      *(bf16x8*)&W2h[r2 * 32 + sw2] = hi;
      *(bf16x8*)&W2l[r2 * 32 + sw2] = lo;
    }
  };

  const f32x4 fz = {0.f, 0.f, 0.f, 0.f};
  f32x4 acc2[4][4];
#pragma unroll
  for (int mf = 0; mf < 4; ++mf)
#pragma unroll
    for (int nf = 0; nf < 4; ++nf) acc2[mf][nf] = fz;

  loadW(0); writeW();
  __syncthreads();

  for (int c = 0; c < NCHUNK; ++c) {
    if (c < NCHUNK - 1) loadW(c + 1);
    float b1v = b1[e * H_HID + c * HC + g1_c + lrow];
    f32x4 acc1[2] = {fz, fz};
#pragma unroll
    for (int kk = 0; kk < 8; ++kk) {
      int k = (kk << 5) + lk8;
      bf16x8 bh = *(const bf16x8*)&W1h[(g1_c + lrow) * WPITCH + k];
      bf16x8 bl = *(const bf16x8*)&W1l[(g1_c + lrow) * WPITCH + k];
#pragma unroll
      for (int mf = 0; mf < 2; ++mf) {
        acc1[mf] = mfma16(xh[mf][kk], bh, acc1[mf]);
        acc1[mf] = mfma16(xh[mf][kk], bl, acc1[mf]);
        acc1[mf] = mfma16(xl[mf][kk], bh, acc1[mf]);
      }
    }
    int acol = g1_c + lrow;
#pragma unroll
    for (int mf = 0; mf < 2; ++mf)
#pragma unroll
      for (int r = 0; r < 4; ++r) {
        float hv = acc1[mf][r] + b1v;
        hv = hv / (1.f + __expf(-hv));
        __bf16 hh = (__bf16)hv;
        __bf16 hl = (__bf16)(hv - (float)hh);
        unsigned pk = (unsigned)__builtin_bit_cast(unsigned short, hh) |
                      ((unsigned)__builtin_bit_cast(unsigned short, hl) << 16);
        int arow = g1_r + (mf << 4) + lr4 + r;
        APK[arow * 32 + ((((acol >> 2) ^ (arow & 7)) << 2) | (acol & 3))] = pk;
      }
    __syncthreads();

    bf16x8 bh2[4], bl2[4];
#pragma unroll
    for (int nf = 0; nf < 4; ++nf) {
      int dcol = (w << 6) + (nf << 4) + lrow;
      int sw = (((lk8 >> 3) ^ (dcol & 3)) << 3);
      bh2[nf] = *(const bf16x8*)&W2h[dcol * 32 + sw];
      bl2[nf] = *(const bf16x8*)&W2l[dcol * 32 + sw];
    }
#pragma unroll
    for (int mf = 0; mf < 4; ++mf) {
      int m = (mf << 4) + lrow, u1 = lk8 >> 2;
      uint4 qa = *(const uint4*)&APK[m * 32 + ((u1 ^ (m & 7)) << 2)];
      uint4 qb = *(const uint4*)&APK[m * 32 + (((u1 + 1) ^ (m & 7)) << 2)];
      U4 ah, al;
      ah.q.x = (qa.x & 0xFFFFu) | (qa.y << 16);
      ah.q.y = (qa.z & 0xFFFFu) | (qa.w << 16);
      ah.q.z = (qb.x & 0xFFFFu) | (qb.y << 16);
      ah.q.w = (qb.z & 0xFFFFu) | (qb.w << 16);
      al.q.x = (qa.x >> 16) | (qa.y & 0xFFFF0000u);
      al.q.y = (qa.z >> 16) | (qa.w & 0xFFFF0000u);
      al.q.z = (qb.x >> 16) | (qb.y & 0xFFFF0000u);
      al.q.w = (qb.z >> 16) | (qb.w & 0xFFFF0000u);
#pragma unroll
      for (int nf = 0; nf < 4; ++nf) {
        acc2[mf][nf] = mfma16(ah.v, bh2[nf], acc2[mf][nf]);
        acc2[mf][nf] = mfma16(ah.v, bl2[nf], acc2[mf][nf]);
        acc2[mf][nf] = mfma16(al.v, bh2[nf], acc2[mf][nf]);
      }
    }
    __syncthreads();
    if (c < NCHUNK - 1) { writeW(); __syncthreads(); }
  }

#pragma unroll
  for (int mf = 0; mf < 4; ++mf)
#pragma unroll
    for (int r = 0; r < 4; ++r) {
      int trow = (mf << 4) + lr4 + r;
#pragma unroll
      for (int nf = 0; nf < 4; ++nf) {
        int dcol = (w << 6) + (nf << 4) + lrow;
        ob[trow * D_MOD + dcol] = acc2[mf][nf][r] + b2[e * D_MOD + dcol]
                                + xb[trow * D_MOD + dcol];
      }
    }
}

extern "C" void kernel_launch(void* const* d_in, const int* in_sizes, int n_in,
                              void* d_out, int out_size, void* d_ws, size_t ws_size,
                              hipStream_t stream) {
  const float* x  = (const float*)d_in[0];
  const float* W1 = (const float*)d_in[1];
  const float* b1 = (const float*)d_in[2];
  const float* W2 = (const float*)d_in[3];
  const float* b2 = (const float*)d_in[4];
  float* out = (float*)d_out;
  __bf16* ws = (__bf16*)d_ws;

  dim3 grid(N_EXP * (T_TOK / BT));   // 2048
  dim3 block(NTHREADS);

  if (ws_size >= WS_NEEDED) {
    hipLaunchKernelGGL(presplit_w, dim3(2048), dim3(256), 0, stream, W1, W2, ws);
    hipLaunchKernelGGL(pmlp_fused, grid, block, 0, stream,
                       x, b1, b2, out, (const __bf16*)ws);
  } else {
    hipLaunchKernelGGL(pmlp_fb, grid, block, 0, stream, x, W1, b1, W2, b2, out);
  }
}

// Round 5
// 439.713 us; speedup vs baseline: 1.4218x; 1.1235x over previous
//
#include <hip/hip_runtime.h>
#include <hip/hip_bf16.h>

// ParallelMLPs: N=32 experts, T=4096, D=256, H=512, fp32 in/out.
// out[e,t,:] = silu(x[e,t,:].W1[e]^T + b1).W2[e]^T + b2 + x
//
// bf16x3 (hi/lo split) MFMA path. Weights pre-split+pre-swizzled into chunk-
// contiguous bf16 images in d_ws; fused kernel stages them with
// global_load_lds under raw-barrier counted-vmcnt pipelining (T4).
// X A-fragments in registers: ONE 16-row frag per wave (64 VGPR) so total
// V+A regs <= 256 -> guaranteed 2 blocks/CU (round-4 occupancy fix).

#define N_EXP 32
#define T_TOK 4096
#define D_MOD 256
#define H_HID 512

#define BT 64
#define HC 32
#define NCHUNK 16
#define NTHREADS 256

#define NWELEM 4194304ull                 // elems per weight image (32*512*256)
#define WS_NEEDED (8ull * NWELEM)         // 4 images * 2B = 33,554,432 B

typedef __attribute__((ext_vector_type(8))) __bf16 bf16x8;
typedef __attribute__((ext_vector_type(4))) __bf16 bf16x4;
typedef __attribute__((ext_vector_type(4))) float  f32x4;
union U4 { uint4 q; bf16x8 v; };

static __device__ __forceinline__ f32x4 mfma16(bf16x8 a, bf16x8 b, f32x4 c) {
  return __builtin_amdgcn_mfma_f32_16x16x32_bf16(a, b, c, 0, 0, 0);
}

static __device__ __forceinline__ void split8(const float v[8], bf16x8& hi, bf16x8& lo) {
#pragma unroll
  for (int j = 0; j < 8; ++j) {
    float f = v[j];
    __bf16 h = (__bf16)f;
    hi[j] = h;
    lo[j] = (__bf16)(f - (float)h);
  }
}

// async global->LDS, 16B/lane; LDS dest wave-uniform (HW adds lane*16)
static __device__ __forceinline__ void gl_lds16(const __bf16* g, __bf16* l) {
  __builtin_amdgcn_global_load_lds(
      (const __attribute__((address_space(1))) void*)g,
      (__attribute__((address_space(3))) void*)l, 16, 0, 0);
}

#define BAR_LGKM() do { asm volatile("s_waitcnt lgkmcnt(0)" ::: "memory"); \
  __builtin_amdgcn_s_barrier(); __builtin_amdgcn_sched_barrier(0); } while (0)
#define BAR_VM(n) do { asm volatile("s_waitcnt vmcnt(" #n ")" ::: "memory"); \
  __builtin_amdgcn_s_barrier(); __builtin_amdgcn_sched_barrier(0); } while (0)

// ---------------------------------------------------------------------------
// Pre-pass: split W1,W2 fp32 -> bf16 hi/lo, chunk-contiguous + XOR-swizzled
// exactly as the fused kernel's LDS wants them (m173: swizzle on global side).
// ws elems: [W1h | W1l | W2h | W2l], each NWELEM.
//  W1 image: unit(e,hrow,u) -> (e*512+hrow)*32 + (u ^ (hrow&7))        u=col>>3
//  W2 image: unit(e,d,u)    -> ((e*16+c)*256+d)*4 + ((u&3) ^ ((d>>1)&3)), c=u>>2
// ---------------------------------------------------------------------------
__global__ __launch_bounds__(256)
void presplit_w(const float* __restrict__ W1, const float* __restrict__ W2,
                __bf16* __restrict__ ws) {
  unsigned U = blockIdx.x * 256 + threadIdx.x;   // one 8-elem unit
  {
    unsigned row = U >> 5;                       // e*512 + hrow
    unsigned u   = U & 31;
    const float* src = W1 + ((size_t)U << 3);
    float4 a0 = *(const float4*)src, a1 = *(const float4*)(src + 4);
    float v[8] = {a0.x, a0.y, a0.z, a0.w, a1.x, a1.y, a1.z, a1.w};
    bf16x8 hi, lo; split8(v, hi, lo);
    size_t dst = (((size_t)row << 5) | (u ^ (row & 7))) << 3;
    *(bf16x8*)(ws + dst)          = hi;
    *(bf16x8*)(ws + NWELEM + dst) = lo;
  }
  {
    unsigned r = U >> 6;                         // e*256 + d
    unsigned e = r >> 8, d = r & 255;
    unsigned u = U & 63;
    unsigned c = u >> 2, uc = u & 3;
    const float* src = W2 + ((size_t)U << 3);
    float4 a0 = *(const float4*)src, a1 = *(const float4*)(src + 4);
    float v[8] = {a0.x, a0.y, a0.z, a0.w, a1.x, a1.y, a1.z, a1.w};
    bf16x8 hi, lo; split8(v, hi, lo);
    size_t dst = (((((size_t)((e << 4) + c) << 8) + d) << 2) | (uc ^ ((d >> 1) & 3))) << 3;
    *(bf16x8*)(ws + 2 * NWELEM + dst) = hi;
    *(bf16x8*)(ws + 3 * NWELEM + dst) = lo;
  }
}

// ---------------------------------------------------------------------------
// Main fused kernel (presplit path)
// ---------------------------------------------------------------------------
__global__ __launch_bounds__(NTHREADS, 2)
void pmlp_fused(const float* __restrict__ x, const float* __restrict__ b1g,
                const float* __restrict__ b2g, float* __restrict__ out,
                const __bf16* __restrict__ wsp) {
  // 74 KB LDS -> 2 blocks/CU
  __shared__ __bf16 W1h[HC * D_MOD],   W1l[HC * D_MOD];     // 2 x 16 KB (swizzled)
  __shared__ __bf16 W2h[D_MOD * HC],   W2l[D_MOD * HC];     // 2 x 16 KB (swizzled)
  __shared__ unsigned APK[BT * 32];                         // 8 KB packed act hi|lo
  __shared__ float b1s[H_HID];                              // 2 KB

  const int tid = threadIdx.x;

  // XCD swizzle: expert e's 64 blocks land on one XCD -> weights L2-resident
  const int p    = blockIdx.x;
  const int xcd  = p & 7;
  const int slot = p >> 3;
  const int e    = xcd + ((slot >> 6) << 3);
  const int ti   = slot & 63;

  const float* xb = x + ((size_t)e * T_TOK + (size_t)ti * BT) * D_MOD;
  float*       ob = out + ((size_t)e * T_TOK + (size_t)ti * BT) * D_MOD;

  const int l    = tid & 63;
  const int w    = tid >> 6;
  const int lrow = l & 15;
  const int lk8  = (l >> 4) << 3;
  const int lr4  = (l >> 4) << 2;
  const int g1_r = w << 4;          // wave's 16-row X group (GEMM1 tiling 4rg x 2cf)

  // biases -> LDS
  b1s[tid]       = b1g[e * H_HID + tid];
  b1s[tid + 256] = b1g[e * H_HID + tid + 256];

  // ---- X -> registers (hi/lo), ONE 16-row frag per wave: 64 VGPR total ----
  bf16x8 xh[8], xl[8];
#pragma unroll
  for (int kk = 0; kk < 8; ++kk) {
    const float* s = xb + (g1_r + lrow) * D_MOD + (kk << 5) + lk8;
    float4 u0 = *(const float4*)s;
    float4 u1 = *(const float4*)(s + 4);
    float v[8] = {u0.x, u0.y, u0.z, u0.w, u1.x, u1.y, u1.z, u1.w};
    split8(v, xh[kk], xl[kk]);
  }

  const __bf16* w1h_img = wsp;
  const __bf16* w1l_img = wsp + NWELEM;
  const __bf16* w2h_img = wsp + 2 * NWELEM;
  const __bf16* w2l_img = wsp + 3 * NWELEM;

  auto stageW1 = [&](int c) {
    size_t gb = ((size_t)(e * NCHUNK + c)) << 13;   // *8192 elems
#pragma unroll
    for (int s = 0; s < 4; ++s) {
      int off = ((w << 2) + s) << 9;                // segment*512 elems
      int go  = off + (l << 3);
      gl_lds16(w1h_img + gb + go, &W1h[off]);
      gl_lds16(w1l_img + gb + go, &W1l[off]);
    }
  };
  auto stageW2 = [&](int c) {
    size_t gb = ((size_t)(e * NCHUNK + c)) << 13;
#pragma unroll
    for (int s = 0; s < 4; ++s) {
      int off = ((w << 2) + s) << 9;
      int go  = off + (l << 3);
      gl_lds16(w2h_img + gb + go, &W2h[off]);
      gl_lds16(w2l_img + gb + go, &W2l[off]);
    }
  };

  const f32x4 fz = {0.f, 0.f, 0.f, 0.f};
  f32x4 acc2[4][4];
#pragma unroll
  for (int mf = 0; mf < 4; ++mf)
#pragma unroll
    for (int nf = 0; nf < 4; ++nf) acc2[mf][nf] = fz;

  // prologue: fence X/bias loads, then stage chunk 0
  asm volatile("" ::: "memory");
  stageW1(0);
  stageW2(0);
  asm volatile("s_waitcnt vmcnt(8)\n\ts_waitcnt lgkmcnt(0)" ::: "memory");
  __builtin_amdgcn_s_barrier();
  __builtin_amdgcn_sched_barrier(0);

  for (int c = 0; c < NCHUNK; ++c) {
    // ---- GEMM1: h[64x32] = X(regs) . W1c^T; wave = 16 rows x 32 cols ----
    f32x4 acc1[2] = {fz, fz};
    __builtin_amdgcn_s_setprio(1);
#pragma unroll
    for (int kk = 0; kk < 8; ++kk) {
#pragma unroll
      for (int cf = 0; cf < 2; ++cf) {
        int r1 = (cf << 4) + lrow;                     // W1 row = h col
        int uu = (((kk << 2) + (lk8 >> 3)) ^ (r1 & 7)) << 3;
        bf16x8 bh = *(const bf16x8*)&W1h[(r1 << 8) + uu];
        bf16x8 bl = *(const bf16x8*)&W1l[(r1 << 8) + uu];
        acc1[cf] = mfma16(xh[kk], bh, acc1[cf]);
        acc1[cf] = mfma16(xh[kk], bl, acc1[cf]);
        acc1[cf] = mfma16(xl[kk], bh, acc1[cf]);
      }
    }
    __builtin_amdgcn_s_setprio(0);
    // bias + silu -> pack hi|lo -> APK (unit-XOR swizzle)
#pragma unroll
    for (int cf = 0; cf < 2; ++cf) {
      int acol = (cf << 4) + lrow;
      float b1v = b1s[c * HC + acol];
#pragma unroll
      for (int r = 0; r < 4; ++r) {
        float hv = acc1[cf][r] + b1v;
        hv = hv / (1.f + __expf(-hv));
        __bf16 hh = (__bf16)hv;
        __bf16 hl = (__bf16)(hv - (float)hh);
        unsigned pk = (unsigned)__builtin_bit_cast(unsigned short, hh) |
                      ((unsigned)__builtin_bit_cast(unsigned short, hl) << 16);
        int arow = g1_r + lr4 + r;
        APK[arow * 32 + ((((acol >> 2) ^ (arow & 7)) << 2) | (acol & 3))] = pk;
      }
    }
    BAR_LGKM();                        // B1: APK visible; W1[c] reads done

    if (c < NCHUNK - 1) {
      stageW1(c + 1);                  // hides under GEMM2
      BAR_VM(8);                       // B2: W2[c] arrived (oldest 8 retired)
    } else {
      BAR_VM(0);
    }

    // ---- GEMM2: acc2 += act(64x32) . W2c^T ----
    bf16x8 bh2[4], bl2[4];
#pragma unroll
    for (int nf = 0; nf < 4; ++nf) {
      int dcol = (w << 6) + (nf << 4) + lrow;
      int up = (((lk8 >> 3) ^ ((dcol >> 1) & 3)) << 3);
      bh2[nf] = *(const bf16x8*)&W2h[(dcol << 5) + up];
      bl2[nf] = *(const bf16x8*)&W2l[(dcol << 5) + up];
    }
#pragma unroll
    for (int mf = 0; mf < 4; ++mf) {
      int m  = (mf << 4) + lrow;
      int u1 = lk8 >> 2;
      uint4 qa = *(const uint4*)&APK[m * 32 + ((u1 ^ (m & 7)) << 2)];
      uint4 qb = *(const uint4*)&APK[m * 32 + (((u1 + 1) ^ (m & 7)) << 2)];
      U4 ah, al;
      ah.q.x = (qa.x & 0xFFFFu) | (qa.y << 16);
      ah.q.y = (qa.z & 0xFFFFu) | (qa.w << 16);
      ah.q.z = (qb.x & 0xFFFFu) | (qb.y << 16);
      ah.q.w = (qb.z & 0xFFFFu) | (qb.w << 16);
      al.q.x = (qa.x >> 16) | (qa.y & 0xFFFF0000u);
      al.q.y = (qa.z >> 16) | (qa.w & 0xFFFF0000u);
      al.q.z = (qb.x >> 16) | (qb.y & 0xFFFF0000u);
      al.q.w = (qb.z >> 16) | (qb.w & 0xFFFF0000u);
      __builtin_amdgcn_s_setprio(1);
#pragma unroll
      for (int nf = 0; nf < 4; ++nf) {
        acc2[mf][nf] = mfma16(ah.v, bh2[nf], acc2[mf][nf]);
        acc2[mf][nf] = mfma16(ah.v, bl2[nf], acc2[mf][nf]);
        acc2[mf][nf] = mfma16(al.v, bh2[nf], acc2[mf][nf]);
      }
      __builtin_amdgcn_s_setprio(0);
    }
    BAR_LGKM();                        // B3: W2[c]+APK reads done

    if (c < NCHUNK - 1) {
      stageW2(c + 1);                  // hides under next GEMM1
      BAR_VM(8);                       // B4: W1[c+1] arrived
    }
  }

  // ---- epilogue: out = acc2 + b2 + x ----
#pragma unroll
  for (int mf = 0; mf < 4; ++mf)
#pragma unroll
    for (int r = 0; r < 4; ++r) {
      int trow = (mf << 4) + lr4 + r;
#pragma unroll
      for (int nf = 0; nf < 4; ++nf) {
        int dcol = (w << 6) + (nf << 4) + lrow;
        ob[trow * D_MOD + dcol] = acc2[mf][nf][r] + b2g[e * D_MOD + dcol]
                                + xb[trow * D_MOD + dcol];
      }
    }
}

// ---------------------------------------------------------------------------
// Fallback (ws too small): in-kernel split, reg staging, __syncthreads.
// ---------------------------------------------------------------------------
#define WPITCH 264
__global__ __launch_bounds__(NTHREADS, 2)
void pmlp_fb(const float* __restrict__ x, const float* __restrict__ W1,
             const float* __restrict__ b1, const float* __restrict__ W2,
             const float* __restrict__ b2, float* __restrict__ out) {
  __shared__ __bf16 W1h[HC * WPITCH], W1l[HC * WPITCH];
  __shared__ __bf16 W2h[D_MOD * 32],  W2l[D_MOD * 32];
  __shared__ unsigned APK[BT * 32];

  const int tid = threadIdx.x;
  const int p = blockIdx.x, xcd = p & 7, slot = p >> 3;
  const int e = xcd + ((slot >> 6) << 3), ti = slot & 63;
  const float* xb = x + ((size_t)e * T_TOK + (size_t)ti * BT) * D_MOD;
  float*       ob = out + ((size_t)e * T_TOK + (size_t)ti * BT) * D_MOD;
  const int l = tid & 63, w = tid >> 6;
  const int lrow = l & 15, lk8 = (l >> 4) << 3, lr4 = (l >> 4) << 2;
  const int g1_r = w << 4;

  bf16x8 xh[8], xl[8];
#pragma unroll
  for (int kk = 0; kk < 8; ++kk) {
    const float* s = xb + (g1_r + lrow) * D_MOD + (kk << 5) + lk8;
    float4 u0 = *(const float4*)s, u1 = *(const float4*)(s + 4);
    float v[8] = {u0.x, u0.y, u0.z, u0.w, u1.x, u1.y, u1.z, u1.w};
    split8(v, xh[kk], xl[kk]);
  }

  float s1[4][8], s2[4][8];
  auto loadW = [&](int c) {
#pragma unroll
    for (int k2 = 0; k2 < 4; ++k2) {
      int g = tid + (k2 << 8);
      int r1 = g >> 5, c1 = (g & 31) << 3;
      int r2 = g >> 2, c2 = (g & 3) << 3;
      const float* sp1 = W1 + ((size_t)e * H_HID + c * HC + r1) * D_MOD + c1;
      const float* sp2 = W2 + ((size_t)e * D_MOD + r2) * H_HID + c * HC + c2;
      float4 u0 = *(const float4*)sp1, u1 = *(const float4*)(sp1 + 4);
      s1[k2][0]=u0.x; s1[k2][1]=u0.y; s1[k2][2]=u0.z; s1[k2][3]=u0.w;
      s1[k2][4]=u1.x; s1[k2][5]=u1.y; s1[k2][6]=u1.z; s1[k2][7]=u1.w;
      float4 v0 = *(const float4*)sp2, v1 = *(const float4*)(sp2 + 4);
      s2[k2][0]=v0.x; s2[k2][1]=v0.y; s2[k2][2]=v0.z; s2[k2][3]=v0.w;
      s2[k2][4]=v1.x; s2[k2][5]=v1.y; s2[k2][6]=v1.z; s2[k2][7]=v1.w;
    }
  };
  auto writeW = [&]() {
#pragma unroll
    for (int k2 = 0; k2 < 4; ++k2) {
      int g = tid + (k2 << 8);
      int r1 = g >> 5, c1 = (g & 31) << 3;
      int r2 = g >> 2, u2 = g & 3;
      int sw2 = ((u2 ^ (r2 & 3)) << 3);
      bf16x8 hi, lo;
      split8(s1[k2], hi, lo);
      *(bf16x8*)&W1h[r1 * WPITCH + c1] = hi;
      *(bf16x8*)&W1l[r1 * WPITCH + c1] = lo;
      split8(s2[k2], hi, lo);
      *(bf16x8*)&W2h[r2 * 32 + sw2] = hi;
      *(bf16x8*)&W2l[r2 * 32 + sw2] = lo;
    }
  };

  const f32x4 fz = {0.f, 0.f, 0.f, 0.f};
  f32x4 acc2[4][4];
#pragma unroll
  for (int mf = 0; mf < 4; ++mf)
#pragma unroll
    for (int nf = 0; nf < 4; ++nf) acc2[mf][nf] = fz;

  loadW(0); writeW();
  __syncthreads();

  for (int c = 0; c < NCHUNK; ++c) {
    if (c < NCHUNK - 1) loadW(c + 1);
    f32x4 acc1[2] = {fz, fz};
#pragma unroll
    for (int kk = 0; kk < 8; ++kk) {
#pragma unroll
      for (int cf = 0; cf < 2; ++cf) {
        int r1 = (cf << 4) + lrow;
        int k = (kk << 5) + lk8;
        bf16x8 bh = *(const bf16x8*)&W1h[r1 * WPITCH + k];
        bf16x8 bl = *(const bf16x8*)&W1l[r1 * WPITCH + k];
        acc1[cf] = mfma16(xh[kk], bh, acc1[cf]);
        acc1[cf] = mfma16(xh[kk], bl, acc1[cf]);
        acc1[cf] = mfma16(xl[kk], bh, acc1[cf]);
      }
    }
#pragma unroll
    for (int cf = 0; cf < 2; ++cf) {
      int acol = (cf << 4) + lrow;
      float b1v = b1[e * H_HID + c * HC + acol];
#pragma unroll
      for (int r = 0; r < 4; ++r) {
        float hv = acc1[cf][r] + b1v;
        hv = hv / (1.f + __expf(-hv));
        __bf16 hh = (__bf16)hv;
        __bf16 hl = (__bf16)(hv - (float)hh);
        unsigned pk = (unsigned)__builtin_bit_cast(unsigned short, hh) |
                      ((unsigned)__builtin_bit_cast(unsigned short, hl) << 16);
        int arow = g1_r + lr4 + r;
        APK[arow * 32 + ((((acol >> 2) ^ (arow & 7)) << 2) | (acol & 3))] = pk;
      }
    }
    __syncthreads();

    bf16x8 bh2[4], bl2[4];
#pragma unroll
    for (int nf = 0; nf < 4; ++nf) {
      int dcol = (w << 6) + (nf << 4) + lrow;
      int sw = (((lk8 >> 3) ^ (dcol & 3)) << 3);
      bh2[nf] = *(const bf16x8*)&W2h[dcol * 32 + sw];
      bl2[nf] = *(const bf16x8*)&W2l[dcol * 32 + sw];
    }
#pragma unroll
    for (int mf = 0; mf < 4; ++mf) {
      int m = (mf << 4) + lrow, u1 = lk8 >> 2;
      uint4 qa = *(const uint4*)&APK[m * 32 + ((u1 ^ (m & 7)) << 2)];
      uint4 qb = *(const uint4*)&APK[m * 32 + (((u1 + 1) ^ (m & 7)) << 2)];
      U4 ah, al;
      ah.q.x = (qa.x & 0xFFFFu) | (qa.y << 16);
      ah.q.y = (qa.z & 0xFFFFu) | (qa.w << 16);
      ah.q.z = (qb.x & 0xFFFFu) | (qb.y << 16);
      ah.q.w = (qb.z & 0xFFFFu) | (qb.w << 16);
      al.q.x = (qa.x >> 16) | (qa.y & 0xFFFF0000u);
      al.q.y = (qa.z >> 16) | (qa.w & 0xFFFF0000u);
      al.q.z = (qb.x >> 16) | (qb.y & 0xFFFF0000u);
      al.q.w = (qb.z >> 16) | (qb.w & 0xFFFF0000u);
#pragma unroll
      for (int nf = 0; nf < 4; ++nf) {
        acc2[mf][nf] = mfma16(ah.v, bh2[nf], acc2[mf][nf]);
        acc2[mf][nf] = mfma16(ah.v, bl2[nf], acc2[mf][nf]);
        acc2[mf][nf] = mfma16(al.v, bh2[nf], acc2[mf][nf]);
      }
    }
    __syncthreads();
    if (c < NCHUNK - 1) { writeW(); __syncthreads(); }
  }

#pragma unroll
  for (int mf = 0; mf < 4; ++mf)
#pragma unroll
    for (int r = 0; r < 4; ++r) {
      int trow = (mf << 4) + lr4 + r;
#pragma unroll
      for (int nf = 0; nf < 4; ++nf) {
        int dcol = (w << 6) + (nf << 4) + lrow;
        ob[trow * D_MOD + dcol] = acc2[mf][nf][r] + b2[e * D_MOD + dcol]
                                + xb[trow * D_MOD + dcol];
      }
    }
}

extern "C" void kernel_launch(void* const* d_in, const int* in_sizes, int n_in,
                              void* d_out, int out_size, void* d_ws, size_t ws_size,
                              hipStream_t stream) {
  const float* x  = (const float*)d_in[0];
  const float* W1 = (const float*)d_in[1];
  const float* b1 = (const float*)d_in[2];
  const float* W2 = (const float*)d_in[3];
  const float* b2 = (const float*)d_in[4];
  float* out = (float*)d_out;
  __bf16* ws = (__bf16*)d_ws;

  dim3 grid(N_EXP * (T_TOK / BT));   // 2048
  dim3 block(NTHREADS);

  if (ws_size >= WS_NEEDED) {
    hipLaunchKernelGGL(presplit_w, dim3(2048), dim3(256), 0, stream, W1, W2, ws);
    hipLaunchKernelGGL(pmlp_fused, grid, block, 0, stream,
                       x, b1, b2, out, (const __bf16*)ws);
  } else {
    hipLaunchKernelGGL(pmlp_fb, grid, block, 0, stream, x, W1, b1, W2, b2, out);
  }
}

// Round 7
// 433.837 us; speedup vs baseline: 1.4411x; 1.0135x over previous
//
#include <hip/hip_runtime.h>
#include <hip/hip_bf16.h>

// ParallelMLPs: N=32 experts, T=4096, D=256, H=512, fp32 in/out.
// out[e,t,:] = silu(x[e,t,:].W1[e]^T + b1).W2[e]^T + b2 + x
//
// bf16x3 (hi/lo split) MFMA. Weights pre-split into bf16 images in d_ws:
//   W1: chunk-contiguous + XOR-swizzled, staged to LDS via global_load_lds.
//   W2: per-(chunk,wave,frag) lane-contiguous -> loaded DIRECTLY to VGPRs
//       (no LDS: waves read disjoint W2 slices, LDS reuse = 0).
// Activations: separate Ah/Al swizzled LDS arrays (no pack/unpack VALU).
// 2 raw barriers/chunk with counted vmcnt (T4); X frags in regs; XCD swizzle.
// vmcnt counting hazard fix: sched_barrier(0) pins stageW1's gl_lds cluster
// BEFORE the W2 VGPR loads so vmcnt(8) provably covers the 8 gl_lds.

#define N_EXP 32
#define T_TOK 4096
#define D_MOD 256
#define H_HID 512

#define BT 64
#define HC 32
#define NCHUNK 16
#define NTHREADS 256

#define NWELEM 4194304ull                 // elems per weight image (32*512*256)
#define WS_NEEDED (8ull * NWELEM)         // 4 images * 2B = 33,554,432 B

typedef __attribute__((ext_vector_type(8))) __bf16 bf16x8;
typedef __attribute__((ext_vector_type(4))) __bf16 bf16x4;
typedef __attribute__((ext_vector_type(4))) float  f32x4;

static __device__ __forceinline__ f32x4 mfma16(bf16x8 a, bf16x8 b, f32x4 c) {
  return __builtin_amdgcn_mfma_f32_16x16x32_bf16(a, b, c, 0, 0, 0);
}

static __device__ __forceinline__ void split8(const float v[8], bf16x8& hi, bf16x8& lo) {
#pragma unroll
  for (int j = 0; j < 8; ++j) {
    float f = v[j];
    __bf16 h = (__bf16)f;
    hi[j] = h;
    lo[j] = (__bf16)(f - (float)h);
  }
}

static __device__ __forceinline__ void gl_lds16(const __bf16* g, __bf16* l) {
  __builtin_amdgcn_global_load_lds(
      (const __attribute__((address_space(1))) void*)g,
      (__attribute__((address_space(3))) void*)l, 16, 0, 0);
}

#define BAR_LGKM() do { asm volatile("s_waitcnt lgkmcnt(0)" ::: "memory"); \
  __builtin_amdgcn_s_barrier(); __builtin_amdgcn_sched_barrier(0); } while (0)
#define BAR_VM_LGKM(n) do { \
  asm volatile("s_waitcnt vmcnt(" #n ") lgkmcnt(0)" ::: "memory"); \
  __builtin_amdgcn_s_barrier(); __builtin_amdgcn_sched_barrier(0); } while (0)

// ---------------------------------------------------------------------------
// Pre-pass: split W1,W2 fp32 -> bf16 hi/lo images in ws.
// ws elems: [W1h | W1l | W2h | W2l], each NWELEM.
//  W1 image (LDS-staged): unit(e,hrow,u) -> (e*512+hrow)*32 + (u ^ (hrow&7)),
//    u = col>>3. Chunk (e,c) occupies a contiguous 8192-elem block.
//  W2 image (reg-loaded): frag order — for expert e, chunk c, wave w, nf,
//    lane l: col d = w*64+nf*16+(l&15), k = (l>>4)*8+j. Linear unit index
//    V = (((e*16+c)*4 + w)*4 + nf)*64 + l.
// ---------------------------------------------------------------------------
__global__ __launch_bounds__(256)
void presplit_w(const float* __restrict__ W1, const float* __restrict__ W2,
                __bf16* __restrict__ ws) {
  unsigned U = blockIdx.x * 256 + threadIdx.x;   // one 8-elem unit, 0..524287
  {
    unsigned row = U >> 5;                       // e*512 + hrow
    unsigned u   = U & 31;
    const float* src = W1 + ((size_t)U << 3);
    float4 a0 = *(const float4*)src, a1 = *(const float4*)(src + 4);
    float v[8] = {a0.x, a0.y, a0.z, a0.w, a1.x, a1.y, a1.z, a1.w};
    bf16x8 hi, lo; split8(v, hi, lo);
    size_t dst = (((size_t)row << 5) | (u ^ (row & 7))) << 3;
    *(bf16x8*)(ws + dst)          = hi;
    *(bf16x8*)(ws + NWELEM + dst) = lo;
  }
  {
    unsigned uh = U & 63;                        // h-unit within row (h = uh*8+j)
    unsigned r  = U >> 6;                        // e*256 + d
    unsigned e  = r >> 8, d = r & 255;
    unsigned c  = uh >> 2, kg = uh & 3;          // chunk, k-group
    unsigned w  = d >> 6, nf = (d >> 4) & 3;
    unsigned lane = kg * 16 + (d & 15);
    const float* src = W2 + ((size_t)U << 3);    // 8 contiguous h elems
    float4 a0 = *(const float4*)src, a1 = *(const float4*)(src + 4);
    float v[8] = {a0.x, a0.y, a0.z, a0.w, a1.x, a1.y, a1.z, a1.w};
    bf16x8 hi, lo; split8(v, hi, lo);
    size_t V = ((((size_t)(e * 16 + c) * 4 + w) * 4 + nf) * 64 + lane) << 3;
    *(bf16x8*)(ws + 2 * NWELEM + V) = hi;
    *(bf16x8*)(ws + 3 * NWELEM + V) = lo;
  }
}

// ---------------------------------------------------------------------------
// Main fused kernel (presplit path). LDS = 43 KB.
// ---------------------------------------------------------------------------
__global__ __launch_bounds__(NTHREADS, 2)
void pmlp_fused(const float* __restrict__ x, const float* __restrict__ b1g,
                const float* __restrict__ b2g, float* __restrict__ out,
                const __bf16* __restrict__ wsp) {
  __shared__ __bf16 W1h[HC * D_MOD], W1l[HC * D_MOD];   // 2 x 16 KB (swizzled)
  __shared__ __bf16 Ah[BT * HC],     Al[BT * HC];       // 2 x 4 KB (swizzled)
  __shared__ float  b1s[H_HID];                         // 2 KB

  const int tid = threadIdx.x;

  // XCD swizzle: expert e's 64 blocks land on one XCD -> weights L2-resident
  const int p    = blockIdx.x;
  const int xcd  = p & 7;
  const int slot = p >> 3;
  const int e    = xcd + ((slot >> 6) << 3);
  const int ti   = slot & 63;

  const float* xb = x + ((size_t)e * T_TOK + (size_t)ti * BT) * D_MOD;
  float*       ob = out + ((size_t)e * T_TOK + (size_t)ti * BT) * D_MOD;

  const int l    = tid & 63;
  const int w    = tid >> 6;
  const int lrow = l & 15;
  const int lk8  = (l >> 4) << 3;
  const int lr4  = (l >> 4) << 2;
  const int g1_r = w << 4;          // wave's 16 X-rows

  b1s[tid]       = b1g[e * H_HID + tid];
  b1s[tid + 256] = b1g[e * H_HID + tid + 256];

  // ---- X -> registers (hi/lo): 64 VGPR ----
  bf16x8 xh[8], xl[8];
#pragma unroll
  for (int kk = 0; kk < 8; ++kk) {
    const float* s = xb + (g1_r + lrow) * D_MOD + (kk << 5) + lk8;
    float4 u0 = *(const float4*)s;
    float4 u1 = *(const float4*)(s + 4);
    float v[8] = {u0.x, u0.y, u0.z, u0.w, u1.x, u1.y, u1.z, u1.w};
    split8(v, xh[kk], xl[kk]);
  }

  const __bf16* w1h_img = wsp;
  const __bf16* w1l_img = wsp + NWELEM;
  const __bf16* w2h_img = wsp + 2 * NWELEM;
  const __bf16* w2l_img = wsp + 3 * NWELEM;

  // W1 staging: 8 gl_lds per wave (4 segments x hi/lo), LDS linear.
  auto stageW1 = [&](int c) {
    size_t gb = ((size_t)(e * NCHUNK + c)) << 13;   // *8192 elems
#pragma unroll
    for (int s = 0; s < 4; ++s) {
      int off = ((w << 2) + s) << 9;                // segment*512 elems
      int go  = off + (l << 3);
      gl_lds16(w1h_img + gb + go, &W1h[off]);
      gl_lds16(w1l_img + gb + go, &W1l[off]);
    }
    // Pin: all 8 gl_lds are issued BEFORE anything after this point, so the
    // in-loop vmcnt(8) provably retires exactly this cluster (no W2-load
    // hoisting above it). Cost-free; see round-6 audit.
    __builtin_amdgcn_sched_barrier(0);
  };

  // W2 fragments: direct global->VGPR, 8 loads per wave per chunk.
  bf16x8 bh2[4], bl2[4];
  auto loadW2 = [&](int c) {
    size_t base = (((size_t)(e * NCHUNK + c) * 4 + w) * 4) << 9; // *(4*64*8)/4
#pragma unroll
    for (int nf = 0; nf < 4; ++nf) {
      size_t o = base + (((size_t)nf << 6) + l) * 8;
      bh2[nf] = *(const bf16x8*)(w2h_img + o);
      bl2[nf] = *(const bf16x8*)(w2l_img + o);
    }
  };

  const f32x4 fz = {0.f, 0.f, 0.f, 0.f};
  f32x4 acc2[4][4];
#pragma unroll
  for (int mf = 0; mf < 4; ++mf)
#pragma unroll
    for (int nf = 0; nf < 4; ++nf) acc2[mf][nf] = fz;

  // prologue: stage W1[0] (needed at barrier), then W2[0] regs (needed later)
  asm volatile("" ::: "memory");
  stageW1(0);
  loadW2(0);
  asm volatile("s_waitcnt vmcnt(8) lgkmcnt(0)" ::: "memory");
  __builtin_amdgcn_s_barrier();
  __builtin_amdgcn_sched_barrier(0);

  for (int c = 0; c < NCHUNK; ++c) {
    // ---- GEMM1: h[64x32] = X(regs) . W1c^T; 4 acc chains ----
    f32x4 a1e[2] = {fz, fz}, a1o[2] = {fz, fz};
    __builtin_amdgcn_s_setprio(1);
#pragma unroll
    for (int kk = 0; kk < 8; ++kk) {
#pragma unroll
      for (int cf = 0; cf < 2; ++cf) {
        int r1 = (cf << 4) + lrow;                     // W1 row = h col
        int uu = (((kk << 2) + (lk8 >> 3)) ^ (r1 & 7)) << 3;
        bf16x8 bh = *(const bf16x8*)&W1h[(r1 << 8) + uu];
        bf16x8 bl = *(const bf16x8*)&W1l[(r1 << 8) + uu];
        f32x4* acc = (kk & 1) ? &a1o[cf] : &a1e[cf];
        *acc = mfma16(xh[kk], bh, *acc);
        *acc = mfma16(xh[kk], bl, *acc);
        *acc = mfma16(xl[kk], bh, *acc);
      }
    }
    __builtin_amdgcn_s_setprio(0);

    // bias + silu -> Ah/Al (b16 writes, unit-XOR swizzle, no packing)
#pragma unroll
    for (int cf = 0; cf < 2; ++cf) {
      int acol = (cf << 4) + lrow;
      float b1v = b1s[c * HC + acol];
      f32x4 hsum = a1e[cf] + a1o[cf];
#pragma unroll
      for (int r = 0; r < 4; ++r) {
        float hv = hsum[r] + b1v;
        hv = hv / (1.f + __expf(-hv));
        __bf16 hh = (__bf16)hv;
        __bf16 hl = (__bf16)(hv - (float)hh);
        int arow = g1_r + lr4 + r;
        int idx = (arow << 5) + (((acol >> 3) ^ ((arow >> 1) & 3)) << 3) + (acol & 7);
        Ah[idx] = hh;
        Al[idx] = hl;
      }
    }
    BAR_LGKM();                        // B1: A visible; W1[c] reads done

    if (c < NCHUNK - 1) stageW1(c + 1);   // 8 gl_lds (order-pinned); hides under GEMM2

    // ---- GEMM2: acc2 += act(64x32) . W2c^T (W2 in regs) ----
#pragma unroll
    for (int mf = 0; mf < 4; ++mf) {
      int m  = (mf << 4) + lrow;
      int su = ((lk8 >> 3) ^ ((m >> 1) & 3)) << 3;
      bf16x8 ah = *(const bf16x8*)&Ah[(m << 5) + su];
      bf16x8 al = *(const bf16x8*)&Al[(m << 5) + su];
      __builtin_amdgcn_s_setprio(1);
#pragma unroll
      for (int nf = 0; nf < 4; ++nf) {
        acc2[mf][nf] = mfma16(ah, bh2[nf], acc2[mf][nf]);
        acc2[mf][nf] = mfma16(ah, bl2[nf], acc2[mf][nf]);
        acc2[mf][nf] = mfma16(al, bh2[nf], acc2[mf][nf]);
      }
      __builtin_amdgcn_s_setprio(0);
    }

    if (c < NCHUNK - 1) {
      loadW2(c + 1);                   // overwrite W2 regs after last use
      // B3: per-wave vmem queue = [8 W1-stage (pinned oldest), 8 W2-loads]
      // -> vmcnt(8) guarantees W1[c+1] is in LDS; W2 regs may still fly
      // (compiler waits exactly on their first use next iteration).
      BAR_VM_LGKM(8);
    }
  }

  // ---- epilogue: out = acc2 + b2 + x ----
#pragma unroll
  for (int mf = 0; mf < 4; ++mf)
#pragma unroll
    for (int r = 0; r < 4; ++r) {
      int trow = (mf << 4) + lr4 + r;
#pragma unroll
      for (int nf = 0; nf < 4; ++nf) {
        int dcol = (w << 6) + (nf << 4) + lrow;
        ob[trow * D_MOD + dcol] = acc2[mf][nf][r] + b2g[e * D_MOD + dcol]
                                + xb[trow * D_MOD + dcol];
      }
    }
}

// ---------------------------------------------------------------------------
// Fallback (ws too small): in-kernel split, reg staging, __syncthreads.
// ---------------------------------------------------------------------------
#define WPITCH 264
union U4 { uint4 q; bf16x8 v; };
__global__ __launch_bounds__(NTHREADS, 2)
void pmlp_fb(const float* __restrict__ x, const float* __restrict__ W1,
             const float* __restrict__ b1, const float* __restrict__ W2,
             const float* __restrict__ b2, float* __restrict__ out) {
  __shared__ __bf16 W1h[HC * WPITCH], W1l[HC * WPITCH];
  __shared__ __bf16 W2h[D_MOD * 32],  W2l[D_MOD * 32];
  __shared__ unsigned APK[BT * 32];

  const int tid = threadIdx.x;
  const int p = blockIdx.x, xcd = p & 7, slot = p >> 3;
  const int e = xcd + ((slot >> 6) << 3), ti = slot & 63;
  const float* xb = x + ((size_t)e * T_TOK + (size_t)ti * BT) * D_MOD;
  float*       ob = out + ((size_t)e * T_TOK + (size_t)ti * BT) * D_MOD;
  const int l = tid & 63, w = tid >> 6;
  const int lrow = l & 15, lk8 = (l >> 4) << 3, lr4 = (l >> 4) << 2;
  const int g1_r = w << 4;

  bf16x8 xh[8], xl[8];
#pragma unroll
  for (int kk = 0; kk < 8; ++kk) {
    const float* s = xb + (g1_r + lrow) * D_MOD + (kk << 5) + lk8;
    float4 u0 = *(const float4*)s, u1 = *(const float4*)(s + 4);
    float v[8] = {u0.x, u0.y, u0.z, u0.w, u1.x, u1.y, u1.z, u1.w};
    split8(v, xh[kk], xl[kk]);
  }

  float s1[4][8], s2[4][8];
  auto loadW = [&](int c) {
#pragma unroll
    for (int k2 = 0; k2 < 4; ++k2) {
      int g = tid + (k2 << 8);
      int r1 = g >> 5, c1 = (g & 31) << 3;
      int r2 = g >> 2, c2 = (g & 3) << 3;
      const float* sp1 = W1 + ((size_t)e * H_HID + c * HC + r1) * D_MOD + c1;
      const float* sp2 = W2 + ((size_t)e * D_MOD + r2) * H_HID + c * HC + c2;
      float4 u0 = *(const float4*)sp1, u1 = *(const float4*)(sp1 + 4);
      s1[k2][0]=u0.x; s1[k2][1]=u0.y; s1[k2][2]=u0.z; s1[k2][3]=u0.w;
      s1[k2][4]=u1.x; s1[k2][5]=u1.y; s1[k2][6]=u1.z; s1[k2][7]=u1.w;
      float4 v0 = *(const float4*)sp2, v1 = *(const float4*)(sp2 + 4);
      s2[k2][0]=v0.x; s2[k2][1]=v0.y; s2[k2][2]=v0.z; s2[k2][3]=v0.w;
      s2[k2][4]=v1.x; s2[k2][5]=v1.y; s2[k2][6]=v1.z; s2[k2][7]=v1.w;
    }
  };
  auto writeW = [&]() {
#pragma unroll
    for (int k2 = 0; k2 < 4; ++k2) {
      int g = tid + (k2 << 8);
      int r1 = g >> 5, c1 = (g & 31) << 3;
      int r2 = g >> 2, u2 = g & 3;
      int sw2 = ((u2 ^ (r2 & 3)) << 3);
      bf16x8 hi, lo;
      split8(s1[k2], hi, lo);
      *(bf16x8*)&W1h[r1 * WPITCH + c1] = hi;
      *(bf16x8*)&W1l[r1 * WPITCH + c1] = lo;
      split8(s2[k2], hi, lo);
      *(bf16x8*)&W2h[r2 * 32 + sw2] = hi;
      *(bf16x8*)&W2l[r2 * 32 + sw2] = lo;
    }
  };

  const f32x4 fz = {0.f, 0.f, 0.f, 0.f};
  f32x4 acc2[4][4];
#pragma unroll
  for (int mf = 0; mf < 4; ++mf)
#pragma unroll
    for (int nf = 0; nf < 4; ++nf) acc2[mf][nf] = fz;

  loadW(0); writeW();
  __syncthreads();

  for (int c = 0; c < NCHUNK; ++c) {
    if (c < NCHUNK - 1) loadW(c + 1);
    f32x4 acc1[2] = {fz, fz};
#pragma unroll
    for (int kk = 0; kk < 8; ++kk) {
#pragma unroll
      for (int cf = 0; cf < 2; ++cf) {
        int r1 = (cf << 4) + lrow;
        int k = (kk << 5) + lk8;
        bf16x8 bh = *(const bf16x8*)&W1h[r1 * WPITCH + k];
        bf16x8 bl = *(const bf16x8*)&W1l[r1 * WPITCH + k];
        acc1[cf] = mfma16(xh[kk], bh, acc1[cf]);
        acc1[cf] = mfma16(xh[kk], bl, acc1[cf]);
        acc1[cf] = mfma16(xl[kk], bh, acc1[cf]);
      }
    }
#pragma unroll
    for (int cf = 0; cf < 2; ++cf) {
      int acol = (cf << 4) + lrow;
      float b1v = b1[e * H_HID + c * HC + acol];
#pragma unroll
      for (int r = 0; r < 4; ++r) {
        float hv = acc1[cf][r] + b1v;
        hv = hv / (1.f + __expf(-hv));
        __bf16 hh = (__bf16)hv;
        __bf16 hl = (__bf16)(hv - (float)hh);
        unsigned pk = (unsigned)__builtin_bit_cast(unsigned short, hh) |
                      ((unsigned)__builtin_bit_cast(unsigned short, hl) << 16);
        int arow = g1_r + lr4 + r;
        APK[arow * 32 + ((((acol >> 2) ^ (arow & 7)) << 2) | (acol & 3))] = pk;
      }
    }
    __syncthreads();

    bf16x8 bh2[4], bl2[4];
#pragma unroll
    for (int nf = 0; nf < 4; ++nf) {
      int dcol = (w << 6) + (nf << 4) + lrow;
      int sw = (((lk8 >> 3) ^ (dcol & 3)) << 3);
      bh2[nf] = *(const bf16x8*)&W2h[dcol * 32 + sw];
      bl2[nf] = *(const bf16x8*)&W2l[dcol * 32 + sw];
    }
#pragma unroll
    for (int mf = 0; mf < 4; ++mf) {
      int m = (mf << 4) + lrow, u1 = lk8 >> 2;
      uint4 qa = *(const uint4*)&APK[m * 32 + ((u1 ^ (m & 7)) << 2)];
      uint4 qb = *(const uint4*)&APK[m * 32 + (((u1 + 1) ^ (m & 7)) << 2)];
      U4 ah, al;
      ah.q.x = (qa.x & 0xFFFFu) | (qa.y << 16);
      ah.q.y = (qa.z & 0xFFFFu) | (qa.w << 16);
      ah.q.z = (qb.x & 0xFFFFu) | (qb.y << 16);
      ah.q.w = (qb.z & 0xFFFFu) | (qb.w << 16);
      al.q.x = (qa.x >> 16) | (qa.y & 0xFFFF0000u);
      al.q.y = (qa.z >> 16) | (qa.w & 0xFFFF0000u);
      al.q.z = (qb.x >> 16) | (qb.y & 0xFFFF0000u);
      al.q.w = (qb.z >> 16) | (qb.w & 0xFFFF0000u);
#pragma unroll
      for (int nf = 0; nf < 4; ++nf) {
        acc2[mf][nf] = mfma16(ah.v, bh2[nf], acc2[mf][nf]);
        acc2[mf][nf] = mfma16(ah.v, bl2[nf], acc2[mf][nf]);
        acc2[mf][nf] = mfma16(al.v, bh2[nf], acc2[mf][nf]);
      }
    }
    __syncthreads();
    if (c < NCHUNK - 1) { writeW(); __syncthreads(); }
  }

#pragma unroll
  for (int mf = 0; mf < 4; ++mf)
#pragma unroll
    for (int r = 0; r < 4; ++r) {
      int trow = (mf << 4) + lr4 + r;
#pragma unroll
      for (int nf = 0; nf < 4; ++nf) {
        int dcol = (w << 6) + (nf << 4) + lrow;
        ob[trow * D_MOD + dcol] = acc2[mf][nf][r] + b2[e * D_MOD + dcol]
                                + xb[trow * D_MOD + dcol];
      }
    }
}

extern "C" void kernel_launch(void* const* d_in, const int* in_sizes, int n_in,
                              void* d_out, int out_size, void* d_ws, size_t ws_size,
                              hipStream_t stream) {
  const float* x  = (const float*)d_in[0];
  const float* W1 = (const float*)d_in[1];
  const float* b1 = (const float*)d_in[2];
  const float* W2 = (const float*)d_in[3];
  const float* b2 = (const float*)d_in[4];
  float* out = (float*)d_out;
  __bf16* ws = (__bf16*)d_ws;

  dim3 grid(N_EXP * (T_TOK / BT));   // 2048
  dim3 block(NTHREADS);

  if (ws_size >= WS_NEEDED) {
    hipLaunchKernelGGL(presplit_w, dim3(2048), dim3(256), 0, stream, W1, W2, ws);
    hipLaunchKernelGGL(pmlp_fused, grid, block, 0, stream,
                       x, b1, b2, out, (const __bf16*)ws);
  } else {
    hipLaunchKernelGGL(pmlp_fb, grid, block, 0, stream, x, W1, b1, W2, b2, out);
  }
}